// Round 7
// baseline (953.134 us; speedup 1.0000x reference)
//
#include <hip/hip_runtime.h>
#include <cstdint>
#include <cstddef>

#define B_ 4
#define S_ 2048
#define D_ 768
#define F_ 3072
#define E_ 8
#define NTOK (B_*S_)        // 8192
#define NASSIGN (NTOK*2)    // 16384 (every token has exactly 2 experts)
#define RBLK 256            // router blocks (32 tokens each)
#define FBLK 32             // fill blocks (256 tokens each)
#define MAXTILE 136         // max m-tiles: 8 XCDs x 17

typedef unsigned short u16;
typedef __attribute__((ext_vector_type(8))) __bf16 bf16x8;
typedef __attribute__((ext_vector_type(4))) float f32x4;

__device__ __forceinline__ u16 f2bf(float f) {
    unsigned int u = __builtin_bit_cast(unsigned int, f);
    u += 0x7fffu + ((u >> 16) & 1u);   // RNE
    return (u16)(u >> 16);
}

// exact-gelu x*Phi(x) via A&S 7.1.26 erf (|err|<=1.5e-7), branch-free
__device__ __forceinline__ float gelu_f(float v) {
    float z = v * 0.70710678f;
    float a = fabsf(z);
    float t = __builtin_amdgcn_rcpf(1.0f + 0.3275911f * a);
    float poly = t * (0.254829592f + t * (-0.284496736f + t * (1.421413741f +
                 t * (-1.453152027f + t * 1.061405429f))));
    float e = __expf(-z * z);
    float erf_z = copysignf(1.0f - poly * e, z);
    return 0.5f * v * (1.0f + erf_z);
}

// ---------------- init (zero cursors only) ----------------
__global__ void k_init(int* cursors) {
    int t = threadIdx.x;
    if (t < E_) cursors[t] = 0;
}

// ---------------- x fp32 -> bf16 ----------------
__global__ void k_cvt_x(const float* __restrict__ x, u16* __restrict__ xb) {
    int id = blockIdx.x * 256 + threadIdx.x;     // NTOK*D_/4 threads
    float4 v = ((const float4*)x)[id];
    ushort4 o;
    o.x = f2bf(v.x); o.y = f2bf(v.y); o.z = f2bf(v.z); o.w = f2bf(v.w);
    ((ushort4*)xb)[id] = o;
}

// ------------- weight transpose+convert: in[e][R][C] f32 -> out[e][C][R] bf16 -------------
__global__ void k_tcvt(const float* __restrict__ in, u16* __restrict__ out, int R, int C) {
    __shared__ u16 t[32][33];
    int e = blockIdx.z;
    int c0 = blockIdx.x * 32, r0 = blockIdx.y * 32;
    int tx = threadIdx.x & 7;      // col group (4 cols each)
    int ty = threadIdx.x >> 3;     // row 0..31
    const float* ip = in + (size_t)e * R * C + (size_t)(r0 + ty) * C + c0 + tx * 4;
    float4 v = *(const float4*)ip;
    t[tx * 4 + 0][ty] = f2bf(v.x);
    t[tx * 4 + 1][ty] = f2bf(v.y);
    t[tx * 4 + 2][ty] = f2bf(v.z);
    t[tx * 4 + 3][ty] = f2bf(v.w);
    __syncthreads();
    u16* op = out + (size_t)e * C * R + (size_t)(c0 + ty) * R + r0 + tx * 4;
    ushort4 o;
    o.x = t[ty][tx * 4 + 0]; o.y = t[ty][tx * 4 + 1];
    o.z = t[ty][tx * 4 + 2]; o.w = t[ty][tx * 4 + 3];
    *(ushort4*)op = o;
}

// ---------------- router ----------------
__global__ __launch_bounds__(256) void k_router(
    const float* __restrict__ x, const float* __restrict__ Wr,
    float* __restrict__ usage_part, float* __restrict__ z_part,
    int* __restrict__ hist_part,
    int* __restrict__ tk_idx, float* __restrict__ tk_w)
{
    __shared__ float wrt[E_ * D_];
    __shared__ float s_usage[E_];
    __shared__ float s_z;
    __shared__ int   s_hist[E_];
    int tid = threadIdx.x;
    for (int i = tid; i < E_ * D_; i += 256) {
        int d = i >> 3, e = i & 7;
        wrt[e * D_ + d] = Wr[i];
    }
    if (tid < E_) { s_usage[tid] = 0.f; s_hist[tid] = 0; }
    if (tid == 0) s_z = 0.f;
    __syncthreads();

    int w = tid >> 6, lane = tid & 63;
    float u_acc[E_];
    #pragma unroll
    for (int e = 0; e < E_; e++) u_acc[e] = 0.f;
    float z_acc = 0.f;

    for (int it = 0; it < 8; it++) {
        int tok = blockIdx.x * 32 + it * 4 + w;
        float acc[E_];
        #pragma unroll
        for (int e = 0; e < E_; e++) acc[e] = 0.f;
        const float* xr = x + (size_t)tok * D_;
        for (int d = lane; d < D_; d += 64) {
            float xv = xr[d];
            #pragma unroll
            for (int e = 0; e < E_; e++) acc[e] += xv * wrt[e * D_ + d];
        }
        #pragma unroll
        for (int off = 32; off > 0; off >>= 1) {
            #pragma unroll
            for (int e = 0; e < E_; e++) acc[e] += __shfl_down(acc[e], off);
        }
        if (lane == 0) {
            float m = acc[0];
            #pragma unroll
            for (int e = 1; e < E_; e++) m = fmaxf(m, acc[e]);
            float p[E_], s = 0.f;
            #pragma unroll
            for (int e = 0; e < E_; e++) { p[e] = expf(acc[e] - m); s += p[e]; }
            float inv = 1.f / s;
            #pragma unroll
            for (int e = 0; e < E_; e++) { p[e] *= inv; u_acc[e] += p[e]; }
            float lse = m + logf(s);
            z_acc += lse * lse;
            int i1 = 0;
            for (int e = 1; e < E_; e++) if (p[e] > p[i1]) i1 = e;
            int i2 = -1;
            for (int e = 0; e < E_; e++) {
                if (e == i1) continue;
                if (i2 < 0 || p[e] > p[i2]) i2 = e;
            }
            float denom = p[i1] + p[i2] + 1e-8f;
            tk_idx[tok * 2 + 0] = i1; tk_idx[tok * 2 + 1] = i2;
            tk_w[tok * 2 + 0] = p[i1] / denom;
            tk_w[tok * 2 + 1] = p[i2] / denom;
            atomicAdd(&s_hist[i1], 1); atomicAdd(&s_hist[i2], 1);
        }
    }
    if (lane == 0) {
        #pragma unroll
        for (int e = 0; e < E_; e++) atomicAdd(&s_usage[e], u_acc[e]);
        atomicAdd(&s_z, z_acc);
    }
    __syncthreads();
    if (tid < E_) {
        usage_part[blockIdx.x * E_ + tid] = s_usage[tid];
        hist_part[blockIdx.x * E_ + tid]  = s_hist[tid];
    }
    if (tid == 0) z_part[blockIdx.x] = s_z;
}

// ---------------- reduce partials -> counts/offsets/tile-list + scalar losses ----------------
__global__ __launch_bounds__(256) void k_finalize(
    const float* __restrict__ usage_part, const float* __restrict__ z_part,
    const int* __restrict__ hist_part,
    int* __restrict__ counts, int* __restrict__ offsets,
    int* __restrict__ tile_list,      // [0]=ntiles, [1+i]=(m0<<8)|e
    float* __restrict__ out_scalars)
{
    __shared__ float s_u[E_];
    __shared__ float s_z;
    __shared__ int   s_h[E_];
    int tid = threadIdx.x;
    if (tid < E_) { s_u[tid] = 0.f; s_h[tid] = 0; }
    if (tid == 0) s_z = 0.f;
    __syncthreads();

    float u[E_]; int h[E_];
    #pragma unroll
    for (int e = 0; e < E_; e++) { u[e] = usage_part[tid * E_ + e]; h[e] = hist_part[tid * E_ + e]; }
    float z = z_part[tid];
    #pragma unroll
    for (int off = 32; off > 0; off >>= 1) {
        #pragma unroll
        for (int e = 0; e < E_; e++) {
            u[e] += __shfl_down(u[e], off);
            h[e] += __shfl_down(h[e], off);
        }
        z += __shfl_down(z, off);
    }
    if ((tid & 63) == 0) {
        #pragma unroll
        for (int e = 0; e < E_; e++) { atomicAdd(&s_u[e], u[e]); atomicAdd(&s_h[e], h[e]); }
        atomicAdd(&s_z, z);
    }
    __syncthreads();
    if (tid == 0) {
        int o = 0, nt = 0;
        for (int e = 0; e < E_; e++) {
            int c = s_h[e];
            counts[e] = c; offsets[e] = o; o += c;
            for (int m0 = 0; m0 < c; m0 += 128) tile_list[1 + nt++] = (m0 << 8) | e;
        }
        tile_list[0] = nt;
        float uu[E_], mean = 0.f;
        for (int e = 0; e < E_; e++) { uu[e] = s_u[e] / (float)NTOK; mean += uu[e]; }
        mean /= (float)E_;
        float var = 0.f;
        for (int e = 0; e < E_; e++) { float d = uu[e] - mean; var += d * d; }
        var /= (float)E_;
        out_scalars[0] = var / (mean * mean + 1e-8f) * (float)E_ * 0.01f;  // lb_loss
        out_scalars[1] = (s_z / (float)NTOK) * 0.001f;                      // z_loss
    }
}

// ---------------- build compact per-expert assignment lists ----------------
__global__ __launch_bounds__(256) void k_fill(
    const int* __restrict__ tk_idx, const float* __restrict__ tk_w,
    const int* __restrict__ offsets, int* __restrict__ cursors,
    int* __restrict__ assign_token, float* __restrict__ assign_weight)
{
    __shared__ int l_cnt[E_];
    __shared__ int l_base[E_];
    int tid = threadIdx.x;
    if (tid < E_) l_cnt[tid] = 0;
    __syncthreads();
    int t = blockIdx.x * 256 + tid;
    int e0 = tk_idx[t * 2 + 0], e1 = tk_idx[t * 2 + 1];
    int r0 = atomicAdd(&l_cnt[e0], 1);
    int r1 = atomicAdd(&l_cnt[e1], 1);
    __syncthreads();
    if (tid < E_) l_base[tid] = atomicAdd(&cursors[tid], l_cnt[tid]);
    __syncthreads();
    int row0 = offsets[e0] + l_base[e0] + r0;
    int row1 = offsets[e1] + l_base[e1] + r1;
    assign_token[row0] = t; assign_weight[row0] = tk_w[t * 2 + 0];
    assign_token[row1] = t; assign_weight[row1] = tk_w[t * 2 + 1];
}

// =============== LDS-free MFMA K-loop (shared by both GEMMs) ===============
// Per-lane direct global->VGPR fragment loads, register double-buffer, NO barriers.
// frag lane mapping: row = base + i*16 + (lane&15), k = kk + (lane>>4)*8 .. +8.
#define LOAD_FRAGS(av, bv, kk) do { \
    _Pragma("unroll") \
    for (int i = 0; i < 4; i++) av[i] = *(const bf16x8*)(arow[i] + (kk)); \
    _Pragma("unroll") \
    for (int j = 0; j < 4; j++) bv[j] = *(const bf16x8*)(brow[j] + (kk)); \
} while (0)
#define DO_MFMA(av, bv) do { \
    _Pragma("unroll") \
    for (int i = 0; i < 4; i++) \
        _Pragma("unroll") \
        for (int j = 0; j < 4; j++) \
            acc[i][j] = __builtin_amdgcn_mfma_f32_16x16x32_bf16(av[i], bv[j], acc[i][j], 0, 0, 0); \
} while (0)

// ---------------- GEMM1: h = gelu(gather(x) @ W1[e] + b1[e]) ----------------
// 1D grid, XCD-swizzled: xcd=bid&7, j=bid>>3, nx=j/17, mloc=j%17, mt=xcd*17+mloc.
__global__ __launch_bounds__(256) void k_gemm1(
    const u16* __restrict__ xb, const u16* __restrict__ w1t,
    const float* __restrict__ b1,
    const int* __restrict__ counts, const int* __restrict__ offsets,
    const int* __restrict__ tile_list,
    const int* __restrict__ assign_token, u16* __restrict__ h)
{
    int bid = blockIdx.x;
    int xcd = bid & 7;
    int j = bid >> 3;
    int nx = j / 17;
    int mt = xcd * 17 + (j % 17);
    int nt = tile_list[0];
    if (mt >= nt) return;
    int packed = tile_list[1 + mt];
    int e = packed & 0xff;
    int m0 = packed >> 8;
    int cnt = counts[e];
    int off = offsets[e];
    int n0 = nx * 128;

    __shared__ __align__(16) u16 SM[16384];   // epilogue transpose only

    int tid = threadIdx.x;
    int w = tid >> 6, lane = tid & 63;
    int wm = (w >> 1) * 64, wn = (w & 1) * 64;
    int fm = lane & 15;
    int kq = (lane >> 4) * 8;

    // per-lane A row pointers (gathered tokens, clamped) and B row pointers
    const u16* arow[4];
    const u16* brow[4];
    #pragma unroll
    for (int i = 0; i < 4; i++) {
        int g = m0 + wm + i * 16 + fm; if (g > cnt - 1) g = cnt - 1;
        arow[i] = xb + (size_t)assign_token[off + g] * D_ + kq;
    }
    #pragma unroll
    for (int j2 = 0; j2 < 4; j2++)
        brow[j2] = w1t + ((size_t)e * F_ + n0 + wn + j2 * 16 + fm) * D_ + kq;

    f32x4 acc[4][4];
    #pragma unroll
    for (int i = 0; i < 4; i++)
        #pragma unroll
        for (int j2 = 0; j2 < 4; j2++) acc[i][j2] = (f32x4){0.f, 0.f, 0.f, 0.f};

    bf16x8 a0[4], b0v[4], a1[4], b1v[4];
    LOAD_FRAGS(a0, b0v, 0);
    for (int kk = 0; kk < D_; kk += 64) {          // D_/32 = 24 even
        LOAD_FRAGS(a1, b1v, kk + 32);
        DO_MFMA(a0, b0v);
        if (kk + 64 < D_) LOAD_FRAGS(a0, b0v, kk + 64);
        DO_MFMA(a1, b1v);
    }

    // ---- epilogue: gelu+cvt -> per-wave swizzled LDS tile -> coalesced uint4 stores ----
    int rbase = (lane >> 4) * 4;
    u16* tb = SM + w * 4096;          // 64x64 u16 (8 KB), XOR-swizzled by (m&7)
    float biasv[4];
    #pragma unroll
    for (int j2 = 0; j2 < 4; j2++) biasv[j2] = b1[e * F_ + n0 + wn + j2 * 16 + fm];
    #pragma unroll
    for (int i = 0; i < 4; i++)
        #pragma unroll
        for (int j2 = 0; j2 < 4; j2++)
            #pragma unroll
            for (int r = 0; r < 4; r++) {
                int m_l = i * 16 + rbase + r;
                int f_l = j2 * 16 + fm;
                u16 q = f2bf(gelu_f(acc[i][j2][r] + biasv[j2]));
                tb[m_l * 64 + ((((f_l >> 3) ^ (m_l & 7)) << 3) | (f_l & 7))] = q;
            }
    __syncthreads();
    #pragma unroll
    for (int s = 0; s < 8; s++) {
        int m_l = s * 8 + (lane >> 3);
        int c = lane & 7;
        uint4 vv = *(const uint4*)&tb[m_l * 64 + ((c ^ (m_l & 7)) << 3)];
        int m = m0 + wm + m_l;
        if (m < cnt)
            *(uint4*)&h[(size_t)(off + m) * F_ + n0 + wn + c * 8] = vv;
    }
}

// ---------------- GEMM2: out[token] += (h @ W2[e] + b2[e]) * weight (atomic combine) ----------------
// 1D grid, XCD-swizzled: xcd=bid&7, j=bid>>3, mloc=j/6, nx=j%6, mt=xcd*17+mloc.
__global__ __launch_bounds__(256) void k_gemm2(
    const u16* __restrict__ h, const u16* __restrict__ w2t,
    const float* __restrict__ b2,
    const int* __restrict__ counts, const int* __restrict__ offsets,
    const int* __restrict__ tile_list,
    const int* __restrict__ assign_token, const float* __restrict__ assign_weight,
    float* __restrict__ out)
{
    int bid = blockIdx.x;
    int xcd = bid & 7;
    int j = bid >> 3;
    int nx = j % 6;
    int mt = xcd * 17 + (j / 6);
    int nt = tile_list[0];
    if (mt >= nt) return;
    int packed = tile_list[1 + mt];
    int e = packed & 0xff;
    int m0 = packed >> 8;
    int cnt = counts[e];
    int off = offsets[e];
    int n0 = nx * 128;

    int tid = threadIdx.x;
    int w = tid >> 6, lane = tid & 63;
    int wm = (w >> 1) * 64, wn = (w & 1) * 64;
    int fm = lane & 15;
    int kq = (lane >> 4) * 8;

    // rows beyond cnt over-read hbuf slack rows (allocated), masked at store
    const u16* arow[4];
    const u16* brow[4];
    #pragma unroll
    for (int i = 0; i < 4; i++)
        arow[i] = h + (size_t)(off + m0 + wm + i * 16 + fm) * F_ + kq;
    #pragma unroll
    for (int j2 = 0; j2 < 4; j2++)
        brow[j2] = w2t + ((size_t)e * D_ + n0 + wn + j2 * 16 + fm) * F_ + kq;

    f32x4 acc[4][4];
    #pragma unroll
    for (int i = 0; i < 4; i++)
        #pragma unroll
        for (int j2 = 0; j2 < 4; j2++) acc[i][j2] = (f32x4){0.f, 0.f, 0.f, 0.f};

    bf16x8 a0[4], b0v[4], a1[4], b1v[4];
    LOAD_FRAGS(a0, b0v, 0);
    for (int kk = 0; kk < F_; kk += 64) {          // F_/32 = 96 even
        LOAD_FRAGS(a1, b1v, kk + 32);
        DO_MFMA(a0, b0v);
        if (kk + 64 < F_) LOAD_FRAGS(a0, b0v, kk + 64);
        DO_MFMA(a1, b1v);
    }

    int rbase = (lane >> 4) * 4;
    float biasv[4];
    #pragma unroll
    for (int j2 = 0; j2 < 4; j2++) biasv[j2] = b2[e * D_ + n0 + wn + j2 * 16 + fm];
    #pragma unroll
    for (int i = 0; i < 4; i++)
        #pragma unroll
        for (int r = 0; r < 4; r++) {
            int m = m0 + wm + i * 16 + rbase + r;
            if (m < cnt) {
                int t = assign_token[off + m];
                float wg = assign_weight[off + m];
                float* orow = out + (size_t)t * D_ + n0 + wn + fm;
                #pragma unroll
                for (int j2 = 0; j2 < 4; j2++)
                    unsafeAtomicAdd(orow + j2 * 16, (acc[i][j2][r] + biasv[j2]) * wg);
            }
        }
}

extern "C" void kernel_launch(void* const* d_in, const int* in_sizes, int n_in,
                              void* d_out, int out_size, void* d_ws, size_t ws_size,
                              hipStream_t stream)
{
    const float* x  = (const float*)d_in[0];
    const float* Wr = (const float*)d_in[1];
    const float* W1 = (const float*)d_in[2];
    const float* b1 = (const float*)d_in[3];
    const float* W2 = (const float*)d_in[4];
    const float* b2 = (const float*)d_in[5];
    float* out = (float*)d_out;

    char* base = (char*)d_ws;
    size_t o = 0;
    auto alloc = [&](size_t bytes) {
        char* r = base + o;
        o += (bytes + 255) & ~(size_t)255;
        return r;
    };
    int*   counts        = (int*)  alloc(E_ * 4);
    int*   cursors       = (int*)  alloc(E_ * 4);
    int*   offsets       = (int*)  alloc(E_ * 4);
    int*   tile_list     = (int*)  alloc(256 * 4);
    float* usage_part    = (float*)alloc((size_t)RBLK * E_ * 4);
    float* z_part        = (float*)alloc((size_t)RBLK * 4);
    int*   hist_part     = (int*)  alloc((size_t)RBLK * E_ * 4);
    int*   tk_idx        = (int*)  alloc((size_t)NTOK * 2 * 4);
    float* tk_w          = (float*)alloc((size_t)NTOK * 2 * 4);
    int*   assign_token  = (int*)  alloc((size_t)NASSIGN * 4);
    float* assign_weight = (float*)alloc((size_t)NASSIGN * 4);
    u16*   xb            = (u16*)  alloc((size_t)NTOK * D_ * 2);
    u16*   w1t           = (u16*)  alloc((size_t)E_ * F_ * D_ * 2);
    u16*   w2t           = (u16*)  alloc((size_t)E_ * D_ * F_ * 2);
    u16*   hbuf          = (u16*)  alloc((size_t)(NASSIGN + 128) * F_ * 2);  // +128 over-read slack

    hipMemsetAsync(d_out, 0, (size_t)out_size * 4, stream);
    k_init<<<dim3(1), dim3(64), 0, stream>>>(cursors);
    k_cvt_x<<<dim3(NTOK * D_ / 1024), dim3(256), 0, stream>>>(x, xb);
    k_tcvt<<<dim3(F_ / 32, D_ / 32, E_), dim3(256), 0, stream>>>(W1, w1t, D_, F_);
    k_tcvt<<<dim3(D_ / 32, F_ / 32, E_), dim3(256), 0, stream>>>(W2, w2t, F_, D_);
    k_router<<<dim3(RBLK), dim3(256), 0, stream>>>(x, Wr, usage_part, z_part, hist_part, tk_idx, tk_w);
    k_finalize<<<dim3(1), dim3(256), 0, stream>>>(usage_part, z_part, hist_part, counts, offsets,
                                                  tile_list, out + (size_t)NTOK * D_);
    k_fill<<<dim3(FBLK), dim3(256), 0, stream>>>(tk_idx, tk_w, offsets, cursors, assign_token, assign_weight);
    k_gemm1<<<dim3(8 * 17 * (F_ / 128)), dim3(256), 0, stream>>>(xb, w1t, b1, counts, offsets, tile_list,
                                                                 assign_token, hbuf);
    k_gemm2<<<dim3(8 * 17 * (D_ / 128)), dim3(256), 0, stream>>>(hbuf, w2t, b2, counts, offsets, tile_list,
                                                                 assign_token, assign_weight, out);
}